// Round 6
// baseline (17.305 us; speedup 1.0000x reference)
//
#include <hip/hip_runtime.h>
#include <math.h>

#define NMODES 32
#define INV2PI 0.15915494309189535f

typedef short bf16x8 __attribute__((ext_vector_type(8)));  // 8 bf16 (4 VGPRs)
typedef float f32x4  __attribute__((ext_vector_type(4)));  // MFMA C/D

// sin/cos of (2*pi*rev): v_sin/v_cos take REVOLUTIONS; reduce to [0,1) first.
__device__ inline void sincos_rev(float rev, float& s, float& c) {
    float f = rev - floorf(rev);
    s = __builtin_amdgcn_sinf(f);
    c = __builtin_amdgcn_cosf(f);
}

// Truncation split: x = hi + lo, hi = bf16-truncate(x) (exact residual lo).
__device__ inline void split_bf(float x, short& hi, short& lo) {
    const unsigned u = __float_as_uint(x);
    const float xf = __uint_as_float(u & 0xFFFF0000u);
    hi = (short)(u >> 16);
    const float r = x - xf;                         // exact
    lo = (short)(__float_as_uint(r) >> 16);
}

// One 64-thread block per (h, a); wave computes A-slab rows i = r + 16a and
// all four B column-blocks. K[h, 64*i + d] = 2 * sum_k G[i,k] Q[k,d],
//   G[i, m]    =  Re(Ct[m] * exp(dtA[m]*64i)),  G[i, m+32] = -Im(...)
//   Q[m, d]    =  Re(exp(dtA[m]*d)),            Q[m+32, d] =  Im(...)
// MFMA called with operands SWAPPED -> D = (G Q)^T:
//   mfma(X=Qfrag, Y=Gfrag): D[d'=4g+reg][i'=r] = K[h][64*(16a+r) + 16b + 4g + reg]
// so each lane's 4 acc regs are 4 consecutive l -> one dwordx4 store per b.
__global__ __launch_bounds__(64, 4) void ssm_mfma_kernel(
    const float* __restrict__ C_real,      // (H, 32, 2)
    const float* __restrict__ log_dt,      // (H,)
    const float* __restrict__ log_A_real,  // (H, 32)
    const float* __restrict__ A_imag,      // (H, 32)
    float* __restrict__ K,                 // (H, 4096)
    int L)
{
    const int bid  = blockIdx.x;
    const int h    = bid >> 2;
    const int a    = bid & 3;
    const int lane = threadIdx.x;          // 0..63
    const int r    = lane & 15;
    const int g    = lane >> 4;            // this lane's 8 modes: g*8 .. g*8+7

    const float dt = __expf(log_dt[h]);
    const float t  = (float)(64 * (r + 16 * a));   // <= 4032, 6 sig bits

    float dAr_[8], rhi_[8], rlo_[8];
    bf16x8 Ah0, Al0, Ah1, Al1;             // G fragments (this wave's slab)

#pragma unroll
    for (int j = 0; j < 8; ++j) {
        const int m   = g * 8 + j;
        const int idx = h * NMODES + m;
        const float Ar = -__expf(log_A_real[idx]);
        const float Ai = A_imag[idx];
        const float dAr = dt * Ar;
        const float dAi_rev = dt * Ai * INV2PI;     // phase step in revolutions

        // exact 12-bit split of the phase step
        const float rhi = __uint_as_float(__float_as_uint(dAi_rev) & 0xFFFFF000u);
        const float rlo = dAi_rev - rhi;            // exact (Sterbenz)

        // Ct = C * (exp(dtA)-1) / A
        float sn, cs;
        sincos_rev(dAi_rev, sn, cs);
        const float er   = __expf(dAr);
        const float em1r = er * cs - 1.0f;
        const float em1i = er * sn;
        const float inv  = 1.0f / (Ar * Ar + Ai * Ai);
        const float fr   = (em1r * Ar + em1i * Ai) * inv;
        const float fi   = (em1i * Ar - em1r * Ai) * inv;
        const float Cr   = C_real[idx * 2 + 0];
        const float Ci   = C_real[idx * 2 + 1];
        const float Ctr  = Cr * fr - Ci * fi;
        const float Cti  = Cr * fi + Ci * fr;

        // A fragment now (Ct dies here; frees registers for B)
        const float pm = __expf(dAr * t);
        const float p  = rhi * t;                   // exact (12b x 6b)
        const float f  = (p - floorf(p)) + rlo * t; // rlo*t exact
        float zs, zc;
        sincos_rev(f, zs, zc);
        const float gr  = (Ctr * zc - Cti * zs) * pm;
        const float gni = -(Ctr * zs + Cti * zc) * pm;
        short hh, ll;
        split_bf(gr, hh, ll);  Ah0[j] = hh; Al0[j] = ll;
        split_bf(gni, hh, ll); Ah1[j] = hh; Al1[j] = ll;

        dAr_[j] = dAr; rhi_[j] = rhi; rlo_[j] = rlo;
    }

    // B fragments, all four column blocks: Q[m, d], d = r + 16*b
    bf16x8 Qh0[4], Ql0[4], Qh1[4], Ql1[4];
#pragma unroll
    for (int b = 0; b < 4; ++b) {
        const float d = (float)(r + 16 * b);        // < 64: rhi*d exact
#pragma unroll
        for (int j = 0; j < 8; ++j) {
            const float pm = __expf(dAr_[j] * d);
            const float p  = rhi_[j] * d;
            const float f  = (p - floorf(p)) + rlo_[j] * d;
            float qs, qc;
            sincos_rev(f, qs, qc);
            short hh, ll;
            split_bf(pm * qc, hh, ll); Qh0[b][j] = hh; Ql0[b][j] = ll;
            split_bf(pm * qs, hh, ll); Qh1[b][j] = hh; Ql1[b][j] = ll;
        }
    }

    float* __restrict__ base = K + (size_t)h * L + 64 * (16 * a + r) + 4 * g;

#pragma unroll
    for (int b = 0; b < 4; ++b) {
        f32x4 acc = {0.f, 0.f, 0.f, 0.f};
        // hi*hi + lo*hi + hi*lo (lo*lo dropped, ~2^-18)
        acc = __builtin_amdgcn_mfma_f32_16x16x32_bf16(Qh0[b], Ah0, acc, 0, 0, 0);
        acc = __builtin_amdgcn_mfma_f32_16x16x32_bf16(Qh1[b], Ah1, acc, 0, 0, 0);
        acc = __builtin_amdgcn_mfma_f32_16x16x32_bf16(Ql0[b], Ah0, acc, 0, 0, 0);
        acc = __builtin_amdgcn_mfma_f32_16x16x32_bf16(Ql1[b], Ah1, acc, 0, 0, 0);
        acc = __builtin_amdgcn_mfma_f32_16x16x32_bf16(Qh0[b], Al0, acc, 0, 0, 0);
        acc = __builtin_amdgcn_mfma_f32_16x16x32_bf16(Qh1[b], Al1, acc, 0, 0, 0);
        float4 o;
        o.x = 2.0f * acc[0]; o.y = 2.0f * acc[1];
        o.z = 2.0f * acc[2]; o.w = 2.0f * acc[3];
        *(float4*)(base + 16 * b) = o;
    }
}

extern "C" void kernel_launch(void* const* d_in, const int* in_sizes, int n_in,
                              void* d_out, int out_size, void* d_ws, size_t ws_size,
                              hipStream_t stream) {
    const float* C_real     = (const float*)d_in[0];
    const float* log_dt     = (const float*)d_in[1];
    const float* log_A_real = (const float*)d_in[2];
    const float* A_imag     = (const float*)d_in[3];
    float* K = (float*)d_out;

    const int H = in_sizes[1];            // log_dt has H elements
    const int L = out_size / H;           // 4096

    ssm_mfma_kernel<<<H * 4, 64, 0, stream>>>(
        C_real, log_dt, log_A_real, A_imag, K, L);
}

// Round 7
// 12.274 us; speedup vs baseline: 1.4099x; 1.4099x over previous
//
#include <hip/hip_runtime.h>
#include <math.h>

#define NMODES 32
#define INV2PI 0.15915494309189535f

typedef short bf16x8 __attribute__((ext_vector_type(8)));  // 8 bf16 (4 VGPRs)
typedef float f32x4  __attribute__((ext_vector_type(4)));  // MFMA C/D

// sin/cos of (2*pi*rev): v_sin/v_cos take REVOLUTIONS; reduce to [0,1) first.
__device__ inline void sincos_rev(float rev, float& s, float& c) {
    float f = rev - floorf(rev);
    s = __builtin_amdgcn_sinf(f);
    c = __builtin_amdgcn_cosf(f);
}

// Truncation split: x = hi + lo, hi = bf16-truncate(x) (exact residual lo).
__device__ inline void split_bf(float x, short& hi, short& lo) {
    const unsigned u = __float_as_uint(x);
    const float xf = __uint_as_float(u & 0xFFFF0000u);
    hi = (short)(u >> 16);
    const float r = x - xf;                         // exact
    lo = (short)(__float_as_uint(r) >> 16);
}

// One 256-thread block (4 waves) per h. Wave w owns A-slab a=w (rows i=r+16w)
// and computes only B column-block b=w; setup + B shared via LDS.
// K[h, 64*i + d] = 2 * sum_k G[i,k] Q[k,d],
//   G[i, m] = Re(Ct[m] exp(dtA[m] 64i)), G[i, m+32] = -Im(...)
//   Q[m, d] = Re(exp(dtA[m] d)),         Q[m+32, d] =  Im(...)
// MFMA operands SWAPPED -> D = (G Q)^T:
//   mfma(Qfrag, Gfrag): D[4g+reg][r] -> K[h][64*(16w+r) + 16b + 4g + reg]
// so each lane's 4 acc regs are 4 consecutive l -> one dwordx4 store per b.
__global__ __launch_bounds__(256, 4) void ssm_mfma_kernel(
    const float* __restrict__ C_real,      // (H, 32, 2)
    const float* __restrict__ log_dt,      // (H,)
    const float* __restrict__ log_A_real,  // (H, 32)
    const float* __restrict__ A_imag,      // (H, 32)
    float* __restrict__ K,                 // (H, 4096)
    int L)
{
    __shared__ __align__(16) float sDAr[NMODES], sRhi[NMODES], sRlo[NMODES],
                                   sCtr[NMODES], sCti[NMODES];
    __shared__ bf16x8 sB[16][64];          // [b*4+q][lane], 16 KiB

    const int h    = blockIdx.x;
    const int tid  = threadIdx.x;
    const int w    = tid >> 6;             // wave = a-slab = b-block owner
    const int lane = tid & 63;
    const int r    = lane & 15;
    const int g    = lane >> 4;            // lane's 8 modes: g*8 .. g*8+7

    // ---- Phase 1: per-mode setup. Every thread computes mode tid&31
    // (8x redundant, uniform -> all waves busy, no divergence); wave 0 writes.
    {
        const int m   = tid & 31;
        const int idx = h * NMODES + m;
        const float dt = __expf(log_dt[h]);
        const float Ar = -__expf(log_A_real[idx]);
        const float Ai = A_imag[idx];
        const float dAr = dt * Ar;
        const float dAi_rev = dt * Ai * INV2PI;     // phase step in revolutions

        // exact 12-bit split of the phase step
        const float rhi = __uint_as_float(__float_as_uint(dAi_rev) & 0xFFFFF000u);
        const float rlo = dAi_rev - rhi;            // exact (Sterbenz)

        // Ct = C * (exp(dtA)-1) / A
        float sn, cs;
        sincos_rev(dAi_rev, sn, cs);
        const float er   = __expf(dAr);
        const float em1r = er * cs - 1.0f;
        const float em1i = er * sn;
        const float inv  = 1.0f / (Ar * Ar + Ai * Ai);
        const float fr   = (em1r * Ar + em1i * Ai) * inv;
        const float fi   = (em1i * Ar - em1r * Ai) * inv;
        const float Cr   = C_real[idx * 2 + 0];
        const float Ci   = C_real[idx * 2 + 1];
        if (tid < 32) {
            sDAr[m] = dAr; sRhi[m] = rhi; sRlo[m] = rlo;
            sCtr[m] = Cr * fr - Ci * fi;
            sCti[m] = Cr * fi + Ci * fr;
        }
    }
    __syncthreads();

    // ---- Phase 2: read params (16-lane broadcast reads, conflict-free)
    float dAr_[8], rhi_[8], rlo_[8];
#pragma unroll
    for (int j = 0; j < 8; ++j) {
        dAr_[j] = sDAr[g * 8 + j];
        rhi_[j] = sRhi[g * 8 + j];
        rlo_[j] = sRlo[g * 8 + j];
    }

    // A fragments (slab a=w): G = Ct * exp(dtA * 64*(r+16w)); Ct dies per-j.
    bf16x8 Ah0, Al0, Ah1, Al1;
    {
        const float t = (float)(64 * (r + 16 * w));  // <= 4032, 6 sig bits
#pragma unroll
        for (int j = 0; j < 8; ++j) {
            const float Ctr = sCtr[g * 8 + j];
            const float Cti = sCti[g * 8 + j];
            const float pm = __expf(dAr_[j] * t);
            const float p  = rhi_[j] * t;            // exact (12b x 6b)
            const float f  = (p - floorf(p)) + rlo_[j] * t;  // rlo*t exact
            float zs, zc;
            sincos_rev(f, zs, zc);
            const float gr  = (Ctr * zc - Cti * zs) * pm;
            const float gni = -(Ctr * zs + Cti * zc) * pm;
            short hh, ll;
            split_bf(gr, hh, ll);  Ah0[j] = hh; Al0[j] = ll;
            split_bf(gni, hh, ll); Ah1[j] = hh; Al1[j] = ll;
        }
    }

    // B fragments, own column block only (b=w): Q[m, d], d = r + 16*w
    {
        bf16x8 bh0, bl0, bh1, bl1;
        const float d = (float)(r + 16 * w);         // < 64: rhi*d exact
#pragma unroll
        for (int j = 0; j < 8; ++j) {
            const float pm = __expf(dAr_[j] * d);
            const float p  = rhi_[j] * d;
            const float f  = (p - floorf(p)) + rlo_[j] * d;
            float qs, qc;
            sincos_rev(f, qs, qc);
            short hh, ll;
            split_bf(pm * qc, hh, ll); bh0[j] = hh; bl0[j] = ll;
            split_bf(pm * qs, hh, ll); bh1[j] = hh; bl1[j] = ll;
        }
        sB[w * 4 + 0][lane] = bh0;   // lane-contiguous 16B: conflict-free b128
        sB[w * 4 + 1][lane] = bl0;
        sB[w * 4 + 2][lane] = bh1;
        sB[w * 4 + 3][lane] = bl1;
    }
    __syncthreads();

    // ---- Phase 3: 4 b-blocks x 6 MFMA, dwordx4 stores
    float* __restrict__ base = K + (size_t)h * L + 64 * (16 * w + r) + 4 * g;

#pragma unroll
    for (int b = 0; b < 4; ++b) {
        const bf16x8 Qh0 = sB[b * 4 + 0][lane];
        const bf16x8 Ql0 = sB[b * 4 + 1][lane];
        const bf16x8 Qh1 = sB[b * 4 + 2][lane];
        const bf16x8 Ql1 = sB[b * 4 + 3][lane];
        f32x4 acc = {0.f, 0.f, 0.f, 0.f};
        // hi*hi + lo*hi + hi*lo (lo*lo dropped, ~2^-18)
        acc = __builtin_amdgcn_mfma_f32_16x16x32_bf16(Qh0, Ah0, acc, 0, 0, 0);
        acc = __builtin_amdgcn_mfma_f32_16x16x32_bf16(Qh1, Ah1, acc, 0, 0, 0);
        acc = __builtin_amdgcn_mfma_f32_16x16x32_bf16(Ql0, Ah0, acc, 0, 0, 0);
        acc = __builtin_amdgcn_mfma_f32_16x16x32_bf16(Ql1, Ah1, acc, 0, 0, 0);
        acc = __builtin_amdgcn_mfma_f32_16x16x32_bf16(Qh0, Al0, acc, 0, 0, 0);
        acc = __builtin_amdgcn_mfma_f32_16x16x32_bf16(Qh1, Al1, acc, 0, 0, 0);
        float4 o;
        o.x = 2.0f * acc[0]; o.y = 2.0f * acc[1];
        o.z = 2.0f * acc[2]; o.w = 2.0f * acc[3];
        *(float4*)(base + 16 * b) = o;
    }
}

extern "C" void kernel_launch(void* const* d_in, const int* in_sizes, int n_in,
                              void* d_out, int out_size, void* d_ws, size_t ws_size,
                              hipStream_t stream) {
    const float* C_real     = (const float*)d_in[0];
    const float* log_dt     = (const float*)d_in[1];
    const float* log_A_real = (const float*)d_in[2];
    const float* A_imag     = (const float*)d_in[3];
    float* K = (float*)d_out;

    const int H = in_sizes[1];            // log_dt has H elements
    const int L = out_size / H;           // 4096

    ssm_mfma_kernel<<<H, 256, 0, stream>>>(
        C_real, log_dt, log_A_real, A_imag, K, L);
}